// Round 4
// baseline (567.525 us; speedup 1.0000x reference)
//
#include <hip/hip_runtime.h>
#include <math.h>

#define PI2_256 0.024543692606170259674f  // 2*pi/256

// ---------------------------------------------------------------------------
// Dims: B=8, C=64, H=256, W=256, M1=M2=16, MLP_HID=32
// Workspace (floats):
//   Xr [B][C][32][16]        off 0
//   Xi                       off 262144
//   Yr [B][16kx][32m][64o]   off 524288
//   Yi                       off 786432
//   Aw [B][H][32k][64o]      off 1048576  (4194304)
//   skwT[i][o] 64x64         off 5242880  (4096)
//   m1wT[o][j] 64x32         off 5246976  (2048)
//   m2wT[j][o] 32x64         off 5249024  (2048)
// ---------------------------------------------------------------------------

__device__ __forceinline__ float gelu_tanh(float v) {
    float t = 0.7978845608028654f * v * (1.0f + 0.044715f * v * v);
    float at = fabsf(t);
    float e = __expf(-2.0f * at);
    float th = (1.0f - e) / (1.0f + e);
    th = copysignf(th, t);
    return 0.5f * v * (1.0f + th);
}

// ---------------------------------------------------------------------------
// k_prep: one-time weight transposes into workspace.
// ---------------------------------------------------------------------------
__global__ __launch_bounds__(256) void k_prep(const float* __restrict__ skw,
                                              const float* __restrict__ m1w,
                                              const float* __restrict__ m2w,
                                              float* __restrict__ skwT,
                                              float* __restrict__ m1wT,
                                              float* __restrict__ m2wT) {
    int t = blockIdx.x * 256 + threadIdx.x;
    if (t < 4096) {
        int i = t >> 6, o = t & 63;
        skwT[t] = skw[o * 64 + i];
    } else if (t < 6144) {
        int s = t - 4096;
        int o = s >> 5, j = s & 31;
        m1wT[s] = m1w[j * 64 + o];
    } else {
        int s = t - 6144;
        int j = s >> 6, o = s & 63;
        m2wT[s] = m2w[o * 32 + j];
    }
}

// ---------------------------------------------------------------------------
// k_fwd: forward DFT (unchanged from round 3 — known good).
// ---------------------------------------------------------------------------
__global__ __launch_bounds__(256) void k_fwd(const float* __restrict__ x,
                                             float* __restrict__ Xr,
                                             float* __restrict__ Xi) {
    int b = blockIdx.y, c = blockIdx.x;
    const float* img = x + ((size_t)(b * 64 + c)) * 65536;
    __shared__ __align__(16) float xs[16 * 260];
    __shared__ __align__(16) float Ft[256 * 32];
    __shared__ float xwr[256], xwi[256];

    int tid = threadIdx.x;
    int kx = tid & 15;
    int hl = tid >> 4;
    int m16 = tid >> 4;

    {
        int kxb = tid & 15, wg = tid >> 4, w0 = wg * 16;
        float s0, c0;
        __sincosf(PI2_256 * (float)((kxb * w0) & 255), &s0, &c0);
        float cr = c0, ci = -s0;
        float ps, pc;
        __sincosf(PI2_256 * (float)kxb, &ps, &pc);
        float pi_ = -ps;
#pragma unroll
        for (int l = 0; l < 16; ++l) {
            int w = w0 + l;
            Ft[w * 32 + 2 * kxb]     = cr;
            Ft[w * 32 + 2 * kxb + 1] = ci;
            float nc = cr * pc - ci * pi_;
            ci = cr * pi_ + ci * pc;
            cr = nc;
        }
    }

    int f1 = m16, f2 = 240 + m16;
    float p1s, p1c, p2s, p2c;
    __sincosf(PI2_256 * (float)f1, &p1s, &p1c);
    __sincosf(PI2_256 * (float)(f2 & 255), &p2s, &p2c);
    float c1 = 1.f, s1 = 0.f, c2 = 1.f, s2 = 0.f;
    float a1r = 0.f, a1i = 0.f, a2r = 0.f, a2i = 0.f;

    for (int chunk = 0; chunk < 16; ++chunk) {
        int hbase = chunk * 16;
        for (int q = 0; q < 4; ++q) {
            int f4 = tid + q * 256;
            int row = f4 >> 6, col = f4 & 63;
            float4 v = ((const float4*)(img + (hbase + row) * 256))[col];
            ((float4*)xs)[row * 65 + col] = v;
        }
        __syncthreads();

        {
            const float4* xrow = (const float4*)(xs + hl * 260);
            const float2* F2 = (const float2*)Ft;
            float swr = 0.f, swi = 0.f;
#pragma unroll 4
            for (int w4 = 0; w4 < 64; ++w4) {
                float4 xv = xrow[w4];
                float2 f0 = F2[(w4 * 4 + 0) * 16 + kx];
                float2 f1_ = F2[(w4 * 4 + 1) * 16 + kx];
                float2 f2_ = F2[(w4 * 4 + 2) * 16 + kx];
                float2 f3 = F2[(w4 * 4 + 3) * 16 + kx];
                swr += xv.x * f0.x; swi += xv.x * f0.y;
                swr += xv.y * f1_.x; swi += xv.y * f1_.y;
                swr += xv.z * f2_.x; swi += xv.z * f2_.y;
                swr += xv.w * f3.x; swi += xv.w * f3.y;
            }
            xwr[hl * 16 + kx] = swr;
            xwi[hl * 16 + kx] = swi;
        }
        __syncthreads();

        for (int hh = 0; hh < 16; ++hh) {
            float wr = xwr[hh * 16 + kx], wi = xwi[hh * 16 + kx];
            a1r += wr * c1 + wi * s1;  a1i += wi * c1 - wr * s1;
            a2r += wr * c2 + wi * s2;  a2i += wi * c2 - wr * s2;
            float n1 = c1 * p1c - s1 * p1s; s1 = c1 * p1s + s1 * p1c; c1 = n1;
            float n2 = c2 * p2c - s2 * p2s; s2 = c2 * p2s + s2 * p2c; c2 = n2;
        }
        __syncthreads();
    }
    int base = ((b * 64 + c) * 32) * 16;
    Xr[base + m16 * 16 + kx]        = a1r;
    Xi[base + m16 * 16 + kx]        = a1i;
    Xr[base + (m16 + 16) * 16 + kx] = a2r;
    Xi[base + (m16 + 16) * 16 + kx] = a2i;
}

// ---------------------------------------------------------------------------
// k_mix: complex channel mix. grid (8 o-split, 32 m) = 256 blocks.
// ---------------------------------------------------------------------------
__global__ __launch_bounds__(256) void k_mix(const float* __restrict__ Xr,
                                             const float* __restrict__ Xi,
                                             const float* __restrict__ w1r,
                                             const float* __restrict__ w1i,
                                             const float* __restrict__ w2r,
                                             const float* __restrict__ w2i,
                                             float* __restrict__ Yr,
                                             float* __restrict__ Yi) {
    int ob = blockIdx.x;   // 0..7
    int m  = blockIdx.y;   // 0..31
    __shared__ float Xsr[8192], Xsi[8192];   // [b][i][kx]
    int tid = threadIdx.x;
    for (int q = 0; q < 32; ++q) {
        int slot = tid + q * 256;
        int bb = slot >> 10, ii = (slot >> 4) & 63, kk = slot & 15;
        int idx = ((bb * 64 + ii) * 32 + m) * 16 + kk;
        Xsr[slot] = Xr[idx];
        Xsi[slot] = Xi[idx];
    }
    __syncthreads();

    const float* Wr; const float* Wi; int mm;
    if (m < 16) { Wr = w1r; Wi = w1i; mm = m; }
    else        { Wr = w2r; Wi = w2i; mm = m - 16; }

    int kx = tid & 15, og = (tid >> 4) & 7, bh = tid >> 7;  // bh 0..1
    int o = ob * 8 + og;
    float ar[4] = {0, 0, 0, 0}, ai[4] = {0, 0, 0, 0};
    for (int i = 0; i < 64; ++i) {
        int widx = ((i * 64 + o) * 16 + mm) * 16 + kx;
        float wr = Wr[widx], wi = Wi[widx];
#pragma unroll
        for (int t = 0; t < 4; ++t) {
            int bb = bh * 4 + t;
            float xr  = Xsr[(bb << 10) + (i << 4) + kx];
            float xi2 = Xsi[(bb << 10) + (i << 4) + kx];
            ar[t] += xr * wr - xi2 * wi;
            ai[t] += xr * wi + xi2 * wr;
        }
    }
#pragma unroll
    for (int t = 0; t < 4; ++t) {
        int bb = bh * 4 + t;
        int yidx = ((bb * 16 + kx) * 32 + m) * 64 + o;
        Yr[yidx] = ar[t];
        Yi[yidx] = ai[t];
    }
}

// ---------------------------------------------------------------------------
// k_expand: expand modes along h (unchanged from round 3 — known good).
// ---------------------------------------------------------------------------
__global__ __launch_bounds__(256) void k_expand(const float* __restrict__ Yr,
                                                const float* __restrict__ Yi,
                                                float* __restrict__ Aw) {
    int bid = blockIdx.x;
    int hq = bid & 15, kx = (bid >> 4) & 15, b = bid >> 8;
    int tid = threadIdx.x;
    int o = tid & 63, hg = tid >> 6;

    float yr[32], yi[32];
    int ybase = ((b * 16 + kx) * 32) * 64 + o;
#pragma unroll
    for (int mm = 0; mm < 32; ++mm) {
        yr[mm] = Yr[ybase + mm * 64];
        yi[mm] = Yi[ybase + mm * 64];
    }
    float sc = (kx == 0 ? 1.0f : 2.0f) * (1.0f / 65536.0f);

    for (int hl = 0; hl < 4; ++hl) {
        int h = hq * 16 + hg * 4 + hl;
        float sts, stc;
        __sincosf(PI2_256 * (float)h, &sts, &stc);
        float tc = 1.f, ts = 0.f, ur = 0.f, ui = 0.f;
#pragma unroll
        for (int mm = 0; mm < 16; ++mm) {
            ur += yr[mm] * tc - yi[mm] * ts;
            ui += yr[mm] * ts + yi[mm] * tc;
            float nc = tc * stc - ts * sts; ts = tc * sts + ts * stc; tc = nc;
        }
        { float s2, c2; __sincosf(PI2_256 * (float)((240 * h) & 255), &s2, &c2);
          tc = c2; ts = s2; }
#pragma unroll
        for (int mm = 16; mm < 32; ++mm) {
            ur += yr[mm] * tc - yi[mm] * ts;
            ui += yr[mm] * ts + yi[mm] * tc;
            float nc = tc * stc - ts * sts; ts = tc * sts + ts * stc; tc = nc;
        }
        int abase = ((b * 256 + h) * 32 + 2 * kx) * 64 + o;
        Aw[abase]      =  sc * ur;
        Aw[abase + 64] = -sc * ui;
    }
}

// ---------------------------------------------------------------------------
// k_fuse v3: weights via SGPR s_load (readfirstlane-forced uniform), LDS
// serves only the per-lane x/F/h1 operand (1 read per K-step). Block =
// (b, h, w-half): LDS 49.5 KB -> 3 blocks/CU.
// grid 4096, 256 threads = 4 waves; wave owns 16 o (phase 2: 8 j).
// ---------------------------------------------------------------------------
#define FMA16(W0, W1, W2, W3, XV)                                        \
    acc[0].x  += W0.x * XV.x;  acc[0].y  += W0.x * XV.y;                 \
    acc[1].x  += W0.y * XV.x;  acc[1].y  += W0.y * XV.y;                 \
    acc[2].x  += W0.z * XV.x;  acc[2].y  += W0.z * XV.y;                 \
    acc[3].x  += W0.w * XV.x;  acc[3].y  += W0.w * XV.y;                 \
    acc[4].x  += W1.x * XV.x;  acc[4].y  += W1.x * XV.y;                 \
    acc[5].x  += W1.y * XV.x;  acc[5].y  += W1.y * XV.y;                 \
    acc[6].x  += W1.z * XV.x;  acc[6].y  += W1.z * XV.y;                 \
    acc[7].x  += W1.w * XV.x;  acc[7].y  += W1.w * XV.y;                 \
    acc[8].x  += W2.x * XV.x;  acc[8].y  += W2.x * XV.y;                 \
    acc[9].x  += W2.y * XV.x;  acc[9].y  += W2.y * XV.y;                 \
    acc[10].x += W2.z * XV.x;  acc[10].y += W2.z * XV.y;                 \
    acc[11].x += W2.w * XV.x;  acc[11].y += W2.w * XV.y;                 \
    acc[12].x += W3.x * XV.x;  acc[12].y += W3.x * XV.y;                 \
    acc[13].x += W3.y * XV.x;  acc[13].y += W3.y * XV.y;                 \
    acc[14].x += W3.z * XV.x;  acc[14].y += W3.z * XV.y;                 \
    acc[15].x += W3.w * XV.x;  acc[15].y += W3.w * XV.y;

__global__ __launch_bounds__(256, 3) void k_fuse(const float* __restrict__ x,
                                                 const float* __restrict__ Aw,
                                                 const float* __restrict__ skwT,
                                                 const float* __restrict__ skb,
                                                 const float* __restrict__ m1wT,
                                                 const float* __restrict__ m1b,
                                                 const float* __restrict__ m2wT,
                                                 const float* __restrict__ m2b,
                                                 float* __restrict__ out) {
    __shared__ __align__(16) float xs[64 * 132];  // x rows, then x1
    __shared__ __align__(16) float Fh[32 * 132];  // F table, then h1

    int bid = blockIdx.x;
    int wh = bid & 1, h = (bid >> 1) & 255, b = bid >> 9;
    int wb = wh * 128;
    int tid = threadIdx.x;
    int lane = tid & 63, wid = tid >> 6;
    int ob = wid * 16, jb = wid * 8;

    // ---- stage x rows (64 rows x 128 cols), coalesced, conflict-free ----
    for (int q = 0; q < 8; ++q) {
        int f4 = tid + q * 256;
        int row = f4 >> 5, col4 = f4 & 31;
        float4 v = *(const float4*)(x + ((size_t)(b * 64 + row)) * 65536
                                    + (size_t)h * 256 + wb + col4 * 4);
        *(float4*)(xs + row * 132 + col4 * 4) = v;
    }
    // ---- F table: Fh[2k][wc]=cos(th k w), Fh[2k+1][wc]=sin ----
    {
        int wc = tid & 127, khalf = tid >> 7;
        int w = wb + wc;
        float sw, cw;
        __sincosf(PI2_256 * (float)(w & 255), &sw, &cw);
        int k0 = khalf * 8;
        float s, c;
        __sincosf(PI2_256 * (float)((k0 * w) & 255), &s, &c);
#pragma unroll
        for (int kk = 0; kk < 8; ++kk) {
            int k = k0 + kk;
            Fh[(2 * k) * 132 + wc]     = c;
            Fh[(2 * k + 1) * 132 + wc] = s;
            float nc = c * cw - s * sw; s = c * sw + s * cw; c = nc;
        }
    }
    __syncthreads();

    const float* Ab = Aw + ((size_t)(b * 256 + h)) * 2048;

    // ============ phase 1: x1 = skip(x) + spectral + bias ============
    float2 acc[16];
#pragma unroll
    for (int i = 0; i < 16; ++i) acc[i] = make_float2(0.f, 0.f);

    for (int k = 0; k < 64; ++k) {
        int so = __builtin_amdgcn_readfirstlane(k * 64 + ob);
        const float4* wp = (const float4*)(skwT + so);
        float4 w0 = wp[0], w1 = wp[1], w2 = wp[2], w3 = wp[3];
        float2 xv = *(const float2*)(xs + k * 132 + lane * 2);
        FMA16(w0, w1, w2, w3, xv)
    }
    for (int k = 0; k < 32; ++k) {
        int so = __builtin_amdgcn_readfirstlane(k * 64 + ob);
        const float4* wp = (const float4*)(Ab + so);
        float4 w0 = wp[0], w1 = wp[1], w2 = wp[2], w3 = wp[3];
        float2 xv = *(const float2*)(Fh + k * 132 + lane * 2);
        FMA16(w0, w1, w2, w3, xv)
    }
    __syncthreads();   // all reads of xs/Fh done
    {
        int sb = __builtin_amdgcn_readfirstlane(ob);
        const float4* bp = (const float4*)(skb + sb);
        float4 b0 = bp[0], b1 = bp[1], b2 = bp[2], b3 = bp[3];
        float bbv[16] = {b0.x, b0.y, b0.z, b0.w, b1.x, b1.y, b1.z, b1.w,
                         b2.x, b2.y, b2.z, b2.w, b3.x, b3.y, b3.z, b3.w};
#pragma unroll
        for (int i = 0; i < 16; ++i) {
            float2 v = acc[i];
            v.x += bbv[i]; v.y += bbv[i];
            *(float2*)(xs + (ob + i) * 132 + lane * 2) = v;   // x1
        }
    }
    __syncthreads();

    // ============ phase 2: h1 = gelu(w1 . x1 + b1) ============
    float2 a2[8];
#pragma unroll
    for (int i = 0; i < 8; ++i) a2[i] = make_float2(0.f, 0.f);

    for (int o = 0; o < 64; ++o) {
        int so = __builtin_amdgcn_readfirstlane(o * 32 + jb);
        const float4* wp = (const float4*)(m1wT + so);
        float4 u0 = wp[0], u1 = wp[1];
        float2 xv = *(const float2*)(xs + o * 132 + lane * 2);
        a2[0].x += u0.x * xv.x; a2[0].y += u0.x * xv.y;
        a2[1].x += u0.y * xv.x; a2[1].y += u0.y * xv.y;
        a2[2].x += u0.z * xv.x; a2[2].y += u0.z * xv.y;
        a2[3].x += u0.w * xv.x; a2[3].y += u0.w * xv.y;
        a2[4].x += u1.x * xv.x; a2[4].y += u1.x * xv.y;
        a2[5].x += u1.y * xv.x; a2[5].y += u1.y * xv.y;
        a2[6].x += u1.z * xv.x; a2[6].y += u1.z * xv.y;
        a2[7].x += u1.w * xv.x; a2[7].y += u1.w * xv.y;
    }
    {
        int sb = __builtin_amdgcn_readfirstlane(jb);
        const float4* bp = (const float4*)(m1b + sb);
        float4 b0 = bp[0], b1 = bp[1];
        float bbv[8] = {b0.x, b0.y, b0.z, b0.w, b1.x, b1.y, b1.z, b1.w};
#pragma unroll
        for (int i = 0; i < 8; ++i) {
            float2 v = a2[i];
            v.x = gelu_tanh(v.x + bbv[i]);
            v.y = gelu_tanh(v.y + bbv[i]);
            *(float2*)(Fh + (jb + i) * 132 + lane * 2) = v;   // h1
        }
    }
    __syncthreads();

    // ============ phase 3: out = x + w2 . h1 + b2 ============
    float2 res[16];
#pragma unroll
    for (int i = 0; i < 16; ++i) {
        res[i] = *(const float2*)(x + ((size_t)(b * 64 + ob + i)) * 65536
                                  + (size_t)h * 256 + wb + lane * 2);
    }
    {
        float2 acc[16];
#pragma unroll
        for (int i = 0; i < 16; ++i) acc[i] = make_float2(0.f, 0.f);

        for (int j = 0; j < 32; ++j) {
            int so = __builtin_amdgcn_readfirstlane(j * 64 + ob);
            const float4* wp = (const float4*)(m2wT + so);
            float4 w0 = wp[0], w1 = wp[1], w2 = wp[2], w3 = wp[3];
            float2 xv = *(const float2*)(Fh + j * 132 + lane * 2);
            FMA16(w0, w1, w2, w3, xv)
        }
        int sb = __builtin_amdgcn_readfirstlane(ob);
        const float4* bp = (const float4*)(m2b + sb);
        float4 b0 = bp[0], b1 = bp[1], b2 = bp[2], b3 = bp[3];
        float bbv[16] = {b0.x, b0.y, b0.z, b0.w, b1.x, b1.y, b1.z, b1.w,
                         b2.x, b2.y, b2.z, b2.w, b3.x, b3.y, b3.z, b3.w};
#pragma unroll
        for (int i = 0; i < 16; ++i) {
            float2 v = acc[i];
            float2 r = res[i];
            v.x += bbv[i] + r.x; v.y += bbv[i] + r.y;
            *(float2*)(out + ((size_t)(b * 64 + ob + i)) * 65536
                       + (size_t)h * 256 + wb + lane * 2) = v;
        }
    }
}

// ---------------------------------------------------------------------------
extern "C" void kernel_launch(void* const* d_in, const int* in_sizes, int n_in,
                              void* d_out, int out_size, void* d_ws, size_t ws_size,
                              hipStream_t stream) {
    const float* x   = (const float*)d_in[0];
    const float* w1r = (const float*)d_in[1];
    const float* w1i = (const float*)d_in[2];
    const float* w2r = (const float*)d_in[3];
    const float* w2i = (const float*)d_in[4];
    const float* skw = (const float*)d_in[5];
    const float* skb = (const float*)d_in[6];
    const float* m1w = (const float*)d_in[7];
    const float* m1b = (const float*)d_in[8];
    const float* m2w = (const float*)d_in[9];
    const float* m2b = (const float*)d_in[10];
    float* out = (float*)d_out;

    float* ws = (float*)d_ws;
    float* Xr   = ws;
    float* Xi   = ws + 262144;
    float* Yr   = ws + 524288;
    float* Yi   = ws + 786432;
    float* Aw   = ws + 1048576;
    float* skwT = ws + 5242880;
    float* m1wT = ws + 5246976;
    float* m2wT = ws + 5249024;

    hipLaunchKernelGGL(k_prep,   dim3(32),     dim3(256), 0, stream,
                       skw, m1w, m2w, skwT, m1wT, m2wT);
    hipLaunchKernelGGL(k_fwd,    dim3(64, 8),  dim3(256), 0, stream, x, Xr, Xi);
    hipLaunchKernelGGL(k_mix,    dim3(8, 32),  dim3(256), 0, stream,
                       Xr, Xi, w1r, w1i, w2r, w2i, Yr, Yi);
    hipLaunchKernelGGL(k_expand, dim3(2048),   dim3(256), 0, stream, Yr, Yi, Aw);
    hipLaunchKernelGGL(k_fuse,   dim3(4096),   dim3(256), 0, stream,
                       x, Aw, skwT, skb, m1wT, m1b, m2wT, m2b, out);
}

// Round 7
// 414.102 us; speedup vs baseline: 1.3705x; 1.3705x over previous
//
#include <hip/hip_runtime.h>
#include <math.h>
#include <stdint.h>

#define PI2_256 0.024543692606170259674f  // 2*pi/256

// ---------------------------------------------------------------------------
// Dims: B=8, C=64, H=256, W=256, M1=M2=16, MLP_HID=32
// Workspace (floats):
//   Xr [B][C][32][16]        off 0
//   Xi                       off 262144
//   Yr [B][16kx][32m][64o]   off 524288
//   Yi                       off 786432
//   Aw [B][H][32k][64o]      off 1048576  (4194304)
// ---------------------------------------------------------------------------

typedef _Float16 f16x2 __attribute__((ext_vector_type(2)));
typedef _Float16 f16x4 __attribute__((ext_vector_type(4)));
typedef _Float16 f16x8 __attribute__((ext_vector_type(8)));
typedef float f32x4 __attribute__((ext_vector_type(4)));

__device__ __forceinline__ float gelu_tanh(float v) {
    float t = 0.7978845608028654f * v * (1.0f + 0.044715f * v * v);
    float at = fabsf(t);
    float e = __expf(-2.0f * at);
    float th = (1.0f - e) / (1.0f + e);
    th = copysignf(th, t);
    return 0.5f * v * (1.0f + th);
}

// ---------------------------------------------------------------------------
// k_fwd: forward DFT (unchanged — known good).
// ---------------------------------------------------------------------------
__global__ __launch_bounds__(256) void k_fwd(const float* __restrict__ x,
                                             float* __restrict__ Xr,
                                             float* __restrict__ Xi) {
    int b = blockIdx.y, c = blockIdx.x;
    const float* img = x + ((size_t)(b * 64 + c)) * 65536;
    __shared__ __align__(16) float xs[16 * 260];
    __shared__ __align__(16) float Ft[256 * 32];
    __shared__ float xwr[256], xwi[256];

    int tid = threadIdx.x;
    int kx = tid & 15;
    int hl = tid >> 4;
    int m16 = tid >> 4;

    {
        int kxb = tid & 15, wg = tid >> 4, w0 = wg * 16;
        float s0, c0;
        __sincosf(PI2_256 * (float)((kxb * w0) & 255), &s0, &c0);
        float cr = c0, ci = -s0;
        float ps, pc;
        __sincosf(PI2_256 * (float)kxb, &ps, &pc);
        float pi_ = -ps;
#pragma unroll
        for (int l = 0; l < 16; ++l) {
            int w = w0 + l;
            Ft[w * 32 + 2 * kxb]     = cr;
            Ft[w * 32 + 2 * kxb + 1] = ci;
            float nc = cr * pc - ci * pi_;
            ci = cr * pi_ + ci * pc;
            cr = nc;
        }
    }

    int f1 = m16, f2 = 240 + m16;
    float p1s, p1c, p2s, p2c;
    __sincosf(PI2_256 * (float)f1, &p1s, &p1c);
    __sincosf(PI2_256 * (float)(f2 & 255), &p2s, &p2c);
    float c1 = 1.f, s1 = 0.f, c2 = 1.f, s2 = 0.f;
    float a1r = 0.f, a1i = 0.f, a2r = 0.f, a2i = 0.f;

    for (int chunk = 0; chunk < 16; ++chunk) {
        int hbase = chunk * 16;
        for (int q = 0; q < 4; ++q) {
            int f4 = tid + q * 256;
            int row = f4 >> 6, col = f4 & 63;
            float4 v = ((const float4*)(img + (hbase + row) * 256))[col];
            ((float4*)xs)[row * 65 + col] = v;
        }
        __syncthreads();

        {
            const float4* xrow = (const float4*)(xs + hl * 260);
            const float2* F2 = (const float2*)Ft;
            float swr = 0.f, swi = 0.f;
#pragma unroll 4
            for (int w4 = 0; w4 < 64; ++w4) {
                float4 xv = xrow[w4];
                float2 f0 = F2[(w4 * 4 + 0) * 16 + kx];
                float2 f1_ = F2[(w4 * 4 + 1) * 16 + kx];
                float2 f2_ = F2[(w4 * 4 + 2) * 16 + kx];
                float2 f3 = F2[(w4 * 4 + 3) * 16 + kx];
                swr += xv.x * f0.x; swi += xv.x * f0.y;
                swr += xv.y * f1_.x; swi += xv.y * f1_.y;
                swr += xv.z * f2_.x; swi += xv.z * f2_.y;
                swr += xv.w * f3.x; swi += xv.w * f3.y;
            }
            xwr[hl * 16 + kx] = swr;
            xwi[hl * 16 + kx] = swi;
        }
        __syncthreads();

        for (int hh = 0; hh < 16; ++hh) {
            float wr = xwr[hh * 16 + kx], wi = xwi[hh * 16 + kx];
            a1r += wr * c1 + wi * s1;  a1i += wi * c1 - wr * s1;
            a2r += wr * c2 + wi * s2;  a2i += wi * c2 - wr * s2;
            float n1 = c1 * p1c - s1 * p1s; s1 = c1 * p1s + s1 * p1c; c1 = n1;
            float n2 = c2 * p2c - s2 * p2s; s2 = c2 * p2s + s2 * p2c; c2 = n2;
        }
        __syncthreads();
    }
    int base = ((b * 64 + c) * 32) * 16;
    Xr[base + m16 * 16 + kx]        = a1r;
    Xi[base + m16 * 16 + kx]        = a1i;
    Xr[base + (m16 + 16) * 16 + kx] = a2r;
    Xi[base + (m16 + 16) * 16 + kx] = a2i;
}

// ---------------------------------------------------------------------------
// k_mix: complex channel mix (unchanged).
// ---------------------------------------------------------------------------
__global__ __launch_bounds__(256) void k_mix(const float* __restrict__ Xr,
                                             const float* __restrict__ Xi,
                                             const float* __restrict__ w1r,
                                             const float* __restrict__ w1i,
                                             const float* __restrict__ w2r,
                                             const float* __restrict__ w2i,
                                             float* __restrict__ Yr,
                                             float* __restrict__ Yi) {
    int ob = blockIdx.x;   // 0..7
    int m  = blockIdx.y;   // 0..31
    __shared__ float Xsr[8192], Xsi[8192];   // [b][i][kx]
    int tid = threadIdx.x;
    for (int q = 0; q < 32; ++q) {
        int slot = tid + q * 256;
        int bb = slot >> 10, ii = (slot >> 4) & 63, kk = slot & 15;
        int idx = ((bb * 64 + ii) * 32 + m) * 16 + kk;
        Xsr[slot] = Xr[idx];
        Xsi[slot] = Xi[idx];
    }
    __syncthreads();

    const float* Wr; const float* Wi; int mm;
    if (m < 16) { Wr = w1r; Wi = w1i; mm = m; }
    else        { Wr = w2r; Wi = w2i; mm = m - 16; }

    int kx = tid & 15, og = (tid >> 4) & 7, bh = tid >> 7;
    int o = ob * 8 + og;
    float ar[4] = {0, 0, 0, 0}, ai[4] = {0, 0, 0, 0};
    for (int i = 0; i < 64; ++i) {
        int widx = ((i * 64 + o) * 16 + mm) * 16 + kx;
        float wr = Wr[widx], wi = Wi[widx];
#pragma unroll
        for (int t = 0; t < 4; ++t) {
            int bb = bh * 4 + t;
            float xr  = Xsr[(bb << 10) + (i << 4) + kx];
            float xi2 = Xsi[(bb << 10) + (i << 4) + kx];
            ar[t] += xr * wr - xi2 * wi;
            ai[t] += xr * wi + xi2 * wr;
        }
    }
#pragma unroll
    for (int t = 0; t < 4; ++t) {
        int bb = bh * 4 + t;
        int yidx = ((bb * 16 + kx) * 32 + m) * 64 + o;
        Yr[yidx] = ar[t];
        Yi[yidx] = ai[t];
    }
}

// ---------------------------------------------------------------------------
// k_expand: expand modes along h (unchanged).
// ---------------------------------------------------------------------------
__global__ __launch_bounds__(256) void k_expand(const float* __restrict__ Yr,
                                                const float* __restrict__ Yi,
                                                float* __restrict__ Aw) {
    int bid = blockIdx.x;
    int hq = bid & 15, kx = (bid >> 4) & 15, b = bid >> 8;
    int tid = threadIdx.x;
    int o = tid & 63, hg = tid >> 6;

    float yr[32], yi[32];
    int ybase = ((b * 16 + kx) * 32) * 64 + o;
#pragma unroll
    for (int mm = 0; mm < 32; ++mm) {
        yr[mm] = Yr[ybase + mm * 64];
        yi[mm] = Yi[ybase + mm * 64];
    }
    float sc = (kx == 0 ? 1.0f : 2.0f) * (1.0f / 65536.0f);

    for (int hl = 0; hl < 4; ++hl) {
        int h = hq * 16 + hg * 4 + hl;
        float sts, stc;
        __sincosf(PI2_256 * (float)h, &sts, &stc);
        float tc = 1.f, ts = 0.f, ur = 0.f, ui = 0.f;
#pragma unroll
        for (int mm = 0; mm < 16; ++mm) {
            ur += yr[mm] * tc - yi[mm] * ts;
            ui += yr[mm] * ts + yi[mm] * tc;
            float nc = tc * stc - ts * sts; ts = tc * sts + ts * stc; tc = nc;
        }
        { float s2, c2; __sincosf(PI2_256 * (float)((240 * h) & 255), &s2, &c2);
          tc = c2; ts = s2; }
#pragma unroll
        for (int mm = 16; mm < 32; ++mm) {
            ur += yr[mm] * tc - yi[mm] * ts;
            ui += yr[mm] * ts + yi[mm] * tc;
            float nc = tc * stc - ts * sts; ts = tc * sts + ts * stc; tc = nc;
        }
        int abase = ((b * 256 + h) * 32 + 2 * kx) * 64 + o;
        Aw[abase]      =  sc * ur;
        Aw[abase + 64] = -sc * ui;
    }
}

// ---------------------------------------------------------------------------
// k_fuse v5 (MFMA f16, NO inline asm): one block per (b,h), 256 thr = 4 waves.
// Documented fragment layouts via plain C++ LDS access:
//   A-operand: [m=16][K] row-major per tile, lane l reads f16x8 at
//              row (l&15), k = 8*(l>>4)+e  (m92-verified pattern)
//   B-operand: [n=16][K] (= B^T) same pattern. skw/m1w/m2w are already
//              [out][in] row-major = B^T — staged directly, no transpose.
//   C/D: lane l holds D[row=(l>>4)*4+reg][col=l&15]  (m89-verified)
// XT tiles (wave-private): k 0..63 = x channels (later x1), k 64..95 =
// F table (later h1). Row strides padded (104/72/40) for 2-way-free LDS.
// ~77 KB LDS -> 2 blocks/CU. ONE barrier (post-staging).
// ---------------------------------------------------------------------------
#define KS    104                 // XT / B1T row stride (96+8)
#define XT_TS 1664                // 16*KS per tile
#define B1T   26624               // 16 tiles * XT_TS
#define B2T   33280               // B1T + 64*KS
#define B3T   35584               // B2T + 32*72

__global__ __launch_bounds__(256) void k_fuse(const float* __restrict__ x,
                                              const float* __restrict__ Aw,
                                              const float* __restrict__ skw,
                                              const float* __restrict__ skb,
                                              const float* __restrict__ m1w,
                                              const float* __restrict__ m1b,
                                              const float* __restrict__ m2w,
                                              const float* __restrict__ m2b,
                                              float* __restrict__ out) {
    __shared__ __align__(16) _Float16 S[38144];
    __shared__ float biasS[160];

    const int bid = blockIdx.x;
    const int b = bid >> 8, h = bid & 255;
    const int tid = threadIdx.x;
    const int l = tid & 63, wid = tid >> 6;

    const float* Ab = Aw + ((size_t)(b * 256 + h)) * 2048;

    // ---- x -> XT k-cols 0..63: pairs of channels give f16x2 stores ----
    for (int it = 0; it < 8; ++it) {
        int idx = it * 256 + tid;
        int c2 = idx >> 6, w4 = idx & 63;
        const float* px = x + ((size_t)(b * 64 + 2 * c2)) * 65536
                          + (size_t)h * 256 + w4 * 4;
        float4 va = *(const float4*)px;
        float4 vb = *(const float4*)(px + 65536);
        int w0 = w4 * 4;
        int a0 = (w0 >> 4) * XT_TS + (w0 & 15) * KS + 2 * c2;
        *(f16x2*)&S[a0]          = (f16x2){(_Float16)va.x, (_Float16)vb.x};
        *(f16x2*)&S[a0 + KS]     = (f16x2){(_Float16)va.y, (_Float16)vb.y};
        *(f16x2*)&S[a0 + 2 * KS] = (f16x2){(_Float16)va.z, (_Float16)vb.z};
        *(f16x2*)&S[a0 + 3 * KS] = (f16x2){(_Float16)va.w, (_Float16)vb.w};
    }
    // ---- F/256 -> XT k-cols 64..95 (cos at 64+2kx, sin at 65+2kx) ----
    {
        int kx = tid & 15, wg = tid >> 4;
        float sk, ck;
        __sincosf(PI2_256 * (float)kx, &sk, &ck);
        float s, c;
        __sincosf(PI2_256 * (float)((kx * wg * 16) & 255), &s, &c);
        const float f = 1.0f / 256.0f;
#pragma unroll
        for (int i = 0; i < 16; ++i) {
            int a = wg * XT_TS + i * KS + 64 + 2 * kx;
            *(f16x2*)&S[a] = (f16x2){(_Float16)(c * f), (_Float16)(s * f)};
            float nc = c * ck - s * sk; s = c * sk + s * ck; c = nc;
        }
    }
    // ---- skw [o][i] row-major -> B1T rows, k 0..63 ----
    for (int it = 0; it < 4; ++it) {
        int idx = it * 256 + tid;
        int o = idx >> 4, k4 = idx & 15;
        float4 v = *(const float4*)(skw + o * 64 + k4 * 4);
        *(f16x4*)&S[B1T + o * KS + k4 * 4] =
            (f16x4){(_Float16)v.x, (_Float16)v.y, (_Float16)v.z, (_Float16)v.w};
    }
    // ---- 256*Aw [r][o] -> B1T rows, k 64..95 (transpose, scalar) ----
    for (int it = 0; it < 8; ++it) {
        int idx = it * 256 + tid;
        int r = idx >> 6, o = idx & 63;
        S[B1T + o * KS + 64 + r] = (_Float16)(Ab[r * 64 + o] * 256.0f);
    }
    // ---- m1w [j][o] row-major -> B2T (stride 72) ----
    for (int it = 0; it < 2; ++it) {
        int idx = it * 256 + tid;
        int j = idx >> 4, k4 = idx & 15;
        float4 v = *(const float4*)(m1w + j * 64 + k4 * 4);
        *(f16x4*)&S[B2T + j * 72 + k4 * 4] =
            (f16x4){(_Float16)v.x, (_Float16)v.y, (_Float16)v.z, (_Float16)v.w};
    }
    // ---- m2w [o][j] row-major -> B3T (stride 40) ----
    for (int it = 0; it < 2; ++it) {
        int idx = it * 256 + tid;
        int o = idx >> 3, k4 = idx & 7;
        float4 v = *(const float4*)(m2w + o * 32 + k4 * 4);
        *(f16x4*)&S[B3T + o * 40 + k4 * 4] =
            (f16x4){(_Float16)v.x, (_Float16)v.y, (_Float16)v.z, (_Float16)v.w};
    }
    if (tid < 64)       biasS[tid] = skb[tid];
    else if (tid < 96)  biasS[tid] = m1b[tid - 64];
    else if (tid < 160) biasS[tid] = m2b[tid - 96];
    __syncthreads();

    const int colL = l & 15, g = l >> 4, g4 = (l >> 4) * 4;
    const int T = wid * 4;   // wave's first tile

    // ================= P1: x1 = x@skw + F@Aspec + bias =================
    f32x4 acc1[4][4];
#pragma unroll
    for (int mt = 0; mt < 4; ++mt)
#pragma unroll
        for (int nt = 0; nt < 4; ++nt) acc1[mt][nt] = (f32x4)0.0f;

    for (int kt = 0; kt < 3; ++kt) {
        f16x8 af[4], bf[4];
#pragma unroll
        for (int mt = 0; mt < 4; ++mt)
            af[mt] = *(const f16x8*)&S[(T + mt) * XT_TS + colL * KS + kt * 32 + 8 * g];
#pragma unroll
        for (int nt = 0; nt < 4; ++nt)
            bf[nt] = *(const f16x8*)&S[B1T + (nt * 16 + colL) * KS + kt * 32 + 8 * g];
#pragma unroll
        for (int mt = 0; mt < 4; ++mt)
#pragma unroll
            for (int nt = 0; nt < 4; ++nt)
                acc1[mt][nt] = __builtin_amdgcn_mfma_f32_16x16x32_f16(
                    af[mt], bf[nt], acc1[mt][nt], 0, 0, 0);
    }
    // x1 (+bias) back into XT k-cols 0..63  (wave-private tiles)
#pragma unroll
    for (int mt = 0; mt < 4; ++mt)
#pragma unroll
        for (int nt = 0; nt < 4; ++nt) {
            int o = nt * 16 + colL;
            float bk = biasS[o];
#pragma unroll
            for (int r = 0; r < 4; ++r)
                S[(T + mt) * XT_TS + (g4 + r) * KS + o] =
                    (_Float16)(acc1[mt][nt][r] + bk);
        }

    // ================= P2: h1 = gelu(x1@m1w + b1) =================
    f32x4 acc2[4][2];
#pragma unroll
    for (int mt = 0; mt < 4; ++mt)
#pragma unroll
        for (int jt = 0; jt < 2; ++jt) acc2[mt][jt] = (f32x4)0.0f;

    for (int kt = 0; kt < 2; ++kt) {
        f16x8 af[4], bf[2];
#pragma unroll
        for (int mt = 0; mt < 4; ++mt)
            af[mt] = *(const f16x8*)&S[(T + mt) * XT_TS + colL * KS + kt * 32 + 8 * g];
#pragma unroll
        for (int jt = 0; jt < 2; ++jt)
            bf[jt] = *(const f16x8*)&S[B2T + (jt * 16 + colL) * 72 + kt * 32 + 8 * g];
#pragma unroll
        for (int mt = 0; mt < 4; ++mt)
#pragma unroll
            for (int jt = 0; jt < 2; ++jt)
                acc2[mt][jt] = __builtin_amdgcn_mfma_f32_16x16x32_f16(
                    af[mt], bf[jt], acc2[mt][jt], 0, 0, 0);
    }
    // h1 into XT k-cols 64..95 (overwrites F — P1 done, wave-private)
#pragma unroll
    for (int mt = 0; mt < 4; ++mt)
#pragma unroll
        for (int jt = 0; jt < 2; ++jt) {
            int j = jt * 16 + colL;
            float bj = biasS[64 + j];
#pragma unroll
            for (int r = 0; r < 4; ++r)
                S[(T + mt) * XT_TS + (g4 + r) * KS + 64 + j] =
                    (_Float16)gelu_tanh(acc2[mt][jt][r] + bj);
        }

    // ================= P3: out = x + h1@m2w + b2 =================
    f32x4 acc3[4][4];
#pragma unroll
    for (int mt = 0; mt < 4; ++mt)
#pragma unroll
        for (int nt = 0; nt < 4; ++nt) acc3[mt][nt] = (f32x4)0.0f;
    {
        f16x8 af[4], bf[4];
#pragma unroll
        for (int mt = 0; mt < 4; ++mt)
            af[mt] = *(const f16x8*)&S[(T + mt) * XT_TS + colL * KS + 64 + 8 * g];
#pragma unroll
        for (int nt = 0; nt < 4; ++nt)
            bf[nt] = *(const f16x8*)&S[B3T + (nt * 16 + colL) * 40 + 8 * g];
#pragma unroll
        for (int mt = 0; mt < 4; ++mt)
#pragma unroll
            for (int nt = 0; nt < 4; ++nt)
                acc3[mt][nt] = __builtin_amdgcn_mfma_f32_16x16x32_f16(
                    af[mt], bf[nt], acc3[mt][nt], 0, 0, 0);
    }
    // epilogue: residual + bias + coalesced float4 store
#pragma unroll
    for (int nt = 0; nt < 4; ++nt) {
        int o = nt * 16 + colL;
        float bo = biasS[96 + o];
#pragma unroll
        for (int mt = 0; mt < 4; ++mt) {
            int pix = (T + mt) * 16 + g4;
            size_t gi = ((size_t)(b * 64 + o)) * 65536 + (size_t)h * 256 + pix;
            float4 r4 = *(const float4*)(x + gi);
            f32x4 v = acc3[mt][nt];
            float4 ov;
            ov.x = r4.x + v[0] + bo;
            ov.y = r4.y + v[1] + bo;
            ov.z = r4.z + v[2] + bo;
            ov.w = r4.w + v[3] + bo;
            *(float4*)(out + gi) = ov;
        }
    }
}

// ---------------------------------------------------------------------------
extern "C" void kernel_launch(void* const* d_in, const int* in_sizes, int n_in,
                              void* d_out, int out_size, void* d_ws, size_t ws_size,
                              hipStream_t stream) {
    const float* x   = (const float*)d_in[0];
    const float* w1r = (const float*)d_in[1];
    const float* w1i = (const float*)d_in[2];
    const float* w2r = (const float*)d_in[3];
    const float* w2i = (const float*)d_in[4];
    const float* skw = (const float*)d_in[5];
    const float* skb = (const float*)d_in[6];
    const float* m1w = (const float*)d_in[7];
    const float* m1b = (const float*)d_in[8];
    const float* m2w = (const float*)d_in[9];
    const float* m2b = (const float*)d_in[10];
    float* out = (float*)d_out;

    float* ws = (float*)d_ws;
    float* Xr   = ws;
    float* Xi   = ws + 262144;
    float* Yr   = ws + 524288;
    float* Yi   = ws + 786432;
    float* Aw   = ws + 1048576;

    hipLaunchKernelGGL(k_fwd,    dim3(64, 8),  dim3(256), 0, stream, x, Xr, Xi);
    hipLaunchKernelGGL(k_mix,    dim3(8, 32),  dim3(256), 0, stream,
                       Xr, Xi, w1r, w1i, w2r, w2i, Yr, Yi);
    hipLaunchKernelGGL(k_expand, dim3(2048),   dim3(256), 0, stream, Yr, Yi, Aw);
    hipLaunchKernelGGL(k_fuse,   dim3(2048),   dim3(256), 0, stream,
                       x, Aw, skw, skb, m1w, m1b, m2w, m2b, out);
}